// Round 4
// baseline (4593.171 us; speedup 1.0000x reference)
//
#include <hip/hip_runtime.h>
#include <math.h>

#define NB    2
#define NQ    8192
#define NCIN  256
#define NG    4
#define NP    8
#define NGP   32     // G*P
#define NCIMG 32
#define NCOUT 128
#define NVIEW 6
#define GXD   64
#define GYD   64
#define GZD   4

// ---------------------------------------------------------------------------
// feature transpose: [B,N,128,H,W] -> [B,G,N,H,W,32]  (channel-last per group)
// ---------------------------------------------------------------------------
__global__ void transpose_feat(const float* __restrict__ src, float* __restrict__ dst,
                               int H, int W)
{
    const int total = NB * NG * NVIEW * H * W * 32;
    for (int i = blockIdx.x * blockDim.x + threadIdx.x; i < total;
         i += gridDim.x * blockDim.x) {
        int c = i & 31;
        int r = i >> 5;
        int x = r % W;  r /= W;
        int y = r % H;  r /= H;
        int n = r % NVIEW; r /= NVIEW;
        int g = r & 3;  r >>= 2;
        int b = r;
        dst[i] = src[(((size_t)(b * NVIEW + n) * 128 + g * 32 + c) * H + y) * W + x];
    }
}

// ---------------------------------------------------------------------------
// bilinear helpers (zero padding, align_corners=False)
// ---------------------------------------------------------------------------
__device__ __forceinline__ float tapf(const float* __restrict__ base, int H, int W,
                                      int x, int y, int c)
{
    if ((unsigned)x >= (unsigned)W || (unsigned)y >= (unsigned)H) return 0.f;
    return base[(size_t)(y * W + x) * 32 + c];
}

__device__ __forceinline__ float bilin(const float* __restrict__ base, int H, int W,
                                       float u, float v, int c)
{
    float px = u * (float)W - 0.5f;
    float py = v * (float)H - 0.5f;
    // clamp far-out coords so int conversion can't overflow (result is 0 there anyway)
    px = fminf(fmaxf(px, -1.0e8f), 1.0e8f);
    py = fminf(fmaxf(py, -1.0e8f), 1.0e8f);
    float x0f = floorf(px), y0f = floorf(py);
    float wx = px - x0f, wy = py - y0f;
    int x0 = (int)x0f, y0 = (int)y0f;
    float v00 = tapf(base, H, W, x0,     y0,     c);
    float v10 = tapf(base, H, W, x0 + 1, y0,     c);
    float v01 = tapf(base, H, W, x0,     y0 + 1, c);
    float v11 = tapf(base, H, W, x0 + 1, y0 + 1, c);
    return v00 * (1.f - wx) * (1.f - wy) + v10 * wx * (1.f - wy)
         + v01 * (1.f - wx) * wy         + v11 * wx * wy;
}

// ---------------------------------------------------------------------------
// fused per-query kernel: gather -> offset/scale matmul -> softmax ->
// projection/view-select -> msmv bilinear sampling -> agg matmul -> scatter
// one block of 256 threads per (b,q)
// ---------------------------------------------------------------------------
__global__ __launch_bounds__(256) void fused_query_kernel(
    const float* __restrict__ pts_bev, const float* __restrict__ l2i,
    const float* __restrict__ qmask,
    const float* __restrict__ w_off, const float* __restrict__ b_off,
    const float* __restrict__ w_sc,  const float* __restrict__ b_sc,
    const float* __restrict__ w_agg, const float* __restrict__ b_agg,
    const int* __restrict__ vxp, const int* __restrict__ vyp, const int* __restrict__ vzp,
    const float* __restrict__ fT0, const float* __restrict__ fT1,
    const float* __restrict__ fT2, const float* __restrict__ fT3,
    float* __restrict__ xout)
{
    const int bq = blockIdx.x;
    const int b  = bq >> 13;
    const int t  = threadIdx.x;
    const int vx = vxp[bq], vy = vyp[bq], vz = vzp[bq];

    __shared__ float s_pts[NCIN];
    __shared__ float s_off[96];
    __shared__ float s_sw[128];
    __shared__ float s_u[NGP], s_v[NGP];
    __shared__ int   s_view[NGP];
    __shared__ float s_l2i[96];
    __shared__ float s_final[1024];
    __shared__ float s_red[256];

    // gather BEV point feature (one channel per thread)
    s_pts[t] = pts_bev[((size_t)(b * NCIN + t) * GYD + vy) * GXD + vx];
    if (t < 96) s_l2i[t] = l2i[b * 96 + t];
    __syncthreads();

    // offset (96 cols) and scale-logit (128 cols) matmuls: one column per thread
    if (t < 224) {
        const bool isOff = t < 96;
        const float* __restrict__ w = isOff ? w_off : w_sc;
        const int col  = isOff ? t : (t - 96);
        const int ncol = isOff ? 96 : 128;
        float acc = isOff ? b_off[col] : b_sc[col];
        #pragma unroll 8
        for (int k = 0; k < NCIN; ++k)
            acc = fmaf(s_pts[k], w[k * ncol + col], acc);
        if (isOff) s_off[col] = acc; else s_sw[col] = acc;
    }
    __syncthreads();

    // softmax over L=4 + projection + first-valid-view argmax (one gp per thread)
    if (t < NGP) {
        float a0 = s_sw[t * 4 + 0], a1 = s_sw[t * 4 + 1];
        float a2 = s_sw[t * 4 + 2], a3 = s_sw[t * 4 + 3];
        float m  = fmaxf(fmaxf(a0, a1), fmaxf(a2, a3));
        float e0 = expf(a0 - m), e1 = expf(a1 - m), e2 = expf(a2 - m), e3 = expf(a3 - m);
        float inv = 1.f / (e0 + e1 + e2 + e3);
        s_sw[t * 4 + 0] = e0 * inv; s_sw[t * 4 + 1] = e1 * inv;
        s_sw[t * 4 + 2] = e2 * inv; s_sw[t * 4 + 3] = e3 * inv;

        float cx = ((float)vx + 0.5f) * 0.6f - 19.2f;
        float cy = ((float)vy + 0.5f) * 0.6f - 19.2f;
        float cz = ((float)vz + 0.5f) * 0.4f - 1.0f;
        float sx = cx + s_off[t * 3 + 0] * 0.6f;
        float sy = cy + s_off[t * 3 + 1] * 0.6f;
        float sz = cz + s_off[t * 3 + 2] * 0.4f;

        int best = 0; float bu = 0.f, bv = 0.f; bool found = false;
        #pragma unroll
        for (int n = 0; n < NVIEW; ++n) {
            const float* M = &s_l2i[n * 16];
            float px = M[0] * sx + M[1] * sy + M[2]  * sz + M[3];
            float py = M[4] * sx + M[5] * sy + M[6]  * sz + M[7];
            float pz = M[8] * sx + M[9] * sy + M[10] * sz + M[11];
            float homo = fmaxf(pz, 1e-5f);
            float u = px / homo / 704.0f;
            float v = py / homo / 256.0f;
            bool val = (pz > 1e-5f) && (u > 0.f) && (u < 1.f) && (v > 0.f) && (v < 1.f);
            if (n == 0) { bu = u; bv = v; }
            if (val && !found) { found = true; best = n; bu = u; bv = v; }
        }
        s_view[t] = best; s_u[t] = bu; s_v[t] = bv;
    }
    __syncthreads();

    // multi-level multi-view bilinear sampling, softmax-weighted over levels
    for (int item = t; item < 1024; item += 256) {
        const int gp = item >> 5, c = item & 31;
        const int g = gp >> 3, p = gp & 7;
        const int view = s_view[gp];
        const float u = s_u[gp], v = s_v[gp];
        const size_t bgv = (size_t)((b * NG + g) * NVIEW + view);
        float acc = 0.f;
        acc += s_sw[gp * 4 + 0] * bilin(fT0 + bgv * (32 * 88 * 32), 32, 88, u, v, c);
        acc += s_sw[gp * 4 + 1] * bilin(fT1 + bgv * (16 * 44 * 32), 16, 44, u, v, c);
        acc += s_sw[gp * 4 + 2] * bilin(fT2 + bgv * ( 8 * 22 * 32),  8, 22, u, v, c);
        acc += s_sw[gp * 4 + 3] * bilin(fT3 + bgv * ( 4 * 11 * 32),  4, 11, u, v, c);
        s_final[(p * NG + g) * NCIMG + c] = acc;   // final layout: (p, g, c)
    }
    __syncthreads();

    // aggregation matmul: 1024 -> 128, split K across two half-waves
    {
        const int co = t & 127;
        const int k0 = (t >> 7) * 512;
        float acc = 0.f;
        #pragma unroll 8
        for (int k = 0; k < 512; ++k)
            acc = fmaf(s_final[k0 + k], w_agg[(size_t)(k0 + k) * NCOUT + co], acc);
        s_red[t] = acc;
    }
    __syncthreads();
    if (t < 128) {
        float val = s_red[t] + s_red[t + 128] + b_agg[t];
        val *= qmask[bq];
        // scatter into conv input layout: channel = co*GZ + vz
        atomicAdd(&xout[((size_t)(b * 512 + t * 4 + vz) * GYD + vy) * GXD + vx], val);
    }
}

// ---------------------------------------------------------------------------
// direct 3x3 SAME conv + eval-BN + ReLU.  16x16 spatial tile x 4 out-channels
// per block of 256 threads.
// ---------------------------------------------------------------------------
__global__ __launch_bounds__(256) void conv3x3_bn_relu(
    const float* __restrict__ x, const float* __restrict__ w,
    const float* __restrict__ gam, const float* __restrict__ bet,
    float* __restrict__ y, int CI, int CO)
{
    const int cob = blockIdx.x % (CO >> 2);
    const int b   = blockIdx.x / (CO >> 2);
    const int co0 = cob << 2;
    const int ty0 = blockIdx.y << 4, tx0 = blockIdx.z << 4;
    const int tx = threadIdx.x & 15, ty = threadIdx.x >> 4;

    __shared__ float tile[18][20];
    __shared__ float swt[4][9];
    float acc0 = 0.f, acc1 = 0.f, acc2 = 0.f, acc3 = 0.f;

    for (int ci = 0; ci < CI; ++ci) {
        __syncthreads();
        const float* __restrict__ xp = x + ((size_t)(b * CI + ci) << 12);
        for (int i = threadIdx.x; i < 324; i += 256) {
            int r = i / 18, cc = i - r * 18;
            int yy = ty0 + r - 1, xx = tx0 + cc - 1;
            tile[r][cc] = ((unsigned)yy < 64u && (unsigned)xx < 64u)
                              ? xp[(yy << 6) + xx] : 0.f;
        }
        if (threadIdx.x < 36) {
            int o = threadIdx.x / 9, k = threadIdx.x - o * 9;
            swt[o][k] = w[((size_t)(co0 + o) * CI + ci) * 9 + k];
        }
        __syncthreads();
        #pragma unroll
        for (int ky = 0; ky < 3; ++ky)
            #pragma unroll
            for (int kx = 0; kx < 3; ++kx) {
                float xv = tile[ty + ky][tx + kx];
                acc0 = fmaf(xv, swt[0][ky * 3 + kx], acc0);
                acc1 = fmaf(xv, swt[1][ky * 3 + kx], acc1);
                acc2 = fmaf(xv, swt[2][ky * 3 + kx], acc2);
                acc3 = fmaf(xv, swt[3][ky * 3 + kx], acc3);
            }
    }

    const float inv = 0.99999500003749978f;   // 1/sqrt(1+1e-5)
    float accs[4] = {acc0, acc1, acc2, acc3};
    #pragma unroll
    for (int o = 0; o < 4; ++o) {
        int co = co0 + o;
        float val = fmaf(accs[o], gam[co] * inv, bet[co]);
        y[((size_t)(b * CO + co) << 12) + ((ty0 + ty) << 6) + (tx0 + tx)] =
            fmaxf(val, 0.f);
    }
}

// ---------------------------------------------------------------------------
extern "C" void kernel_launch(void* const* d_in, const int* in_sizes, int n_in,
                              void* d_out, int out_size, void* d_ws, size_t ws_size,
                              hipStream_t stream)
{
    const float* feat0    = (const float*)d_in[0];
    const float* feat1    = (const float*)d_in[1];
    const float* feat2    = (const float*)d_in[2];
    const float* feat3    = (const float*)d_in[3];
    const float* pts_bev  = (const float*)d_in[4];
    const float* l2i      = (const float*)d_in[5];
    const float* qmask    = (const float*)d_in[6];
    const int*   vox_x    = (const int*)d_in[7];
    const int*   vox_y    = (const int*)d_in[8];
    const int*   vox_z    = (const int*)d_in[9];
    const float* w_off    = (const float*)d_in[10];
    const float* b_off    = (const float*)d_in[11];
    const float* w_sc     = (const float*)d_in[12];
    const float* b_sc     = (const float*)d_in[13];
    const float* w_agg    = (const float*)d_in[14];
    const float* b_agg    = (const float*)d_in[15];
    const float* conv1_w  = (const float*)d_in[16];
    const float* conv2_w  = (const float*)d_in[17];
    const float* conv3_w  = (const float*)d_in[18];
    const float* conv4_w  = (const float*)d_in[19];
    const float* bn1_g    = (const float*)d_in[20];
    const float* bn1_b    = (const float*)d_in[21];
    const float* bn2_g    = (const float*)d_in[22];
    const float* bn2_b    = (const float*)d_in[23];
    const float* bn3_g    = (const float*)d_in[24];
    const float* bn3_b    = (const float*)d_in[25];
    const float* bn4_g    = (const float*)d_in[26];
    const float* bn4_b    = (const float*)d_in[27];

    // workspace layout (floats) — 12,036,096 floats = 48.1 MB total, with
    // aliasing of dead buffers to minimize footprint:
    //   [fT0|fT1|fT2|fT3] 5,744,640   (features; dead after fused_query)
    //   [x0]              4,194,304   (conv1 in; dead after conv1)
    //   [x1]              2,097,152   (conv1 out / conv2 in)
    //   x2 aliases x0  (conv2 out / conv3 in)
    //   x3 aliases fT0 (conv3 out / conv4 in)
    float* ws  = (float*)d_ws;
    float* fT0 = ws;                       // 2*4*6*32*88*32 = 4,325,376
    float* fT1 = fT0 + 4325376;            // 1,081,344
    float* fT2 = fT1 + 1081344;            //   270,336
    float* fT3 = fT2 + 270336;             //    67,584
    float* x0  = fT3 + 67584;              // [2,512,64,64] = 4,194,304
    float* x1  = x0  + 4194304;            // [2,256,64,64] = 2,097,152
    float* x2  = x0;                       // alias: x0 dead after conv1
    float* x3  = fT0;                      // alias: features dead after fused_query

    hipMemsetAsync(x0, 0, (size_t)4194304 * sizeof(float), stream);

    transpose_feat<<<1024, 256, 0, stream>>>(feat0, fT0, 32, 88);
    transpose_feat<<< 512, 256, 0, stream>>>(feat1, fT1, 16, 44);
    transpose_feat<<< 128, 256, 0, stream>>>(feat2, fT2,  8, 22);
    transpose_feat<<<  64, 256, 0, stream>>>(feat3, fT3,  4, 11);

    fused_query_kernel<<<NB * NQ, 256, 0, stream>>>(
        pts_bev, l2i, qmask, w_off, b_off, w_sc, b_sc, w_agg, b_agg,
        vox_x, vox_y, vox_z, fT0, fT1, fT2, fT3, x0);

    conv3x3_bn_relu<<<dim3(NB * (256 / 4), 4, 4), 256, 0, stream>>>(
        x0, conv1_w, bn1_g, bn1_b, x1, 512, 256);
    conv3x3_bn_relu<<<dim3(NB * (512 / 4), 4, 4), 256, 0, stream>>>(
        x1, conv2_w, bn2_g, bn2_b, x2, 256, 512);
    conv3x3_bn_relu<<<dim3(NB * (512 / 4), 4, 4), 256, 0, stream>>>(
        x2, conv3_w, bn3_g, bn3_b, x3, 512, 512);
    conv3x3_bn_relu<<<dim3(NB * (128 / 4), 4, 4), 256, 0, stream>>>(
        x3, conv4_w, bn4_g, bn4_b, (float*)d_out, 512, 128);
}

// Round 5
// 879.219 us; speedup vs baseline: 5.2241x; 5.2241x over previous
//
#include <hip/hip_runtime.h>
#include <math.h>

#define NB    2
#define NQ    8192
#define NCIN  256
#define NG    4
#define NP    8
#define NGP   32
#define NCIMG 32
#define NCOUT 128
#define NVIEW 6
#define GXD   64
#define GYD   64
#define GZD   4

typedef float f32x4 __attribute__((ext_vector_type(4)));
typedef short s16x8 __attribute__((ext_vector_type(8)));
typedef unsigned short u16;
typedef unsigned int   u32;

// ---- bf16 split helpers (round-to-nearest-even) ----
__device__ __forceinline__ u16 bf16_rne(float f) {
    u32 u = __float_as_uint(f);
    u32 r = (u + 0x7FFFu + ((u >> 16) & 1u)) >> 16;
    return (u16)r;
}
__device__ __forceinline__ float bf16_f(u16 h) {
    return __uint_as_float(((u32)h) << 16);
}

// ---------------------------------------------------------------------------
// feature transpose: [B,N,128,H,W] -> [B,G,N,H,W,32]  (channel-last per group)
// ---------------------------------------------------------------------------
__global__ void transpose_feat(const float* __restrict__ src, float* __restrict__ dst,
                               int H, int W)
{
    const int total = NB * NG * NVIEW * H * W * 32;
    for (int i = blockIdx.x * blockDim.x + threadIdx.x; i < total;
         i += gridDim.x * blockDim.x) {
        int c = i & 31;
        int r = i >> 5;
        int x = r % W;  r /= W;
        int y = r % H;  r /= H;
        int n = r % NVIEW; r /= NVIEW;
        int g = r & 3;  r >>= 2;
        int b = r;
        dst[i] = src[(((size_t)(b * NVIEW + n) * 128 + g * 32 + c) * H + y) * W + x];
    }
}

// small weight transpose: wT[col][k] (col<96: w_off col, else w_sc col-96)
__global__ void pack_wT(const float* __restrict__ w_off, const float* __restrict__ w_sc,
                        float* __restrict__ wT)
{
    int i = blockIdx.x * 256 + threadIdx.x;
    if (i >= 224 * 256) return;
    int col = i >> 8, k = i & 255;
    wT[i] = (col < 96) ? w_off[k * 96 + col] : w_sc[k * 128 + (col - 96)];
}

// conv weight pack: src [CO][CI][3][3] fp32 -> hi/lo bf16 [tap9][CO][CI]
__global__ void pack_conv_w(const float* __restrict__ src, u16* __restrict__ hi,
                            u16* __restrict__ lo, int CI, int CO)
{
    const int N = CO * CI * 9;
    for (int i = blockIdx.x * blockDim.x + threadIdx.x; i < N;
         i += gridDim.x * blockDim.x) {
        int tap = i % 9;
        int r = i / 9;
        int ci = r % CI;
        int co = r / CI;
        float v = src[i];
        u16 h = bf16_rne(v);
        size_t d = ((size_t)tap * CO + co) * CI + ci;
        hi[d] = h;
        lo[d] = bf16_rne(v - bf16_f(h));
    }
}

// ---------------------------------------------------------------------------
// bilinear helpers (zero padding, align_corners=False)
// ---------------------------------------------------------------------------
__device__ __forceinline__ float tapf(const float* __restrict__ base, int H, int W,
                                      int x, int y, int c)
{
    if ((unsigned)x >= (unsigned)W || (unsigned)y >= (unsigned)H) return 0.f;
    return base[(size_t)(y * W + x) * 32 + c];
}

__device__ __forceinline__ float bilin(const float* __restrict__ base, int H, int W,
                                       float u, float v, int c)
{
    float px = u * (float)W - 0.5f;
    float py = v * (float)H - 0.5f;
    px = fminf(fmaxf(px, -1.0e8f), 1.0e8f);
    py = fminf(fmaxf(py, -1.0e8f), 1.0e8f);
    float x0f = floorf(px), y0f = floorf(py);
    float wx = px - x0f, wy = py - y0f;
    int x0 = (int)x0f, y0 = (int)y0f;
    float v00 = tapf(base, H, W, x0,     y0,     c);
    float v10 = tapf(base, H, W, x0 + 1, y0,     c);
    float v01 = tapf(base, H, W, x0,     y0 + 1, c);
    float v11 = tapf(base, H, W, x0 + 1, y0 + 1, c);
    return v00 * (1.f - wx) * (1.f - wy) + v10 * wx * (1.f - wy)
         + v01 * (1.f - wx) * wy         + v11 * wx * wy;
}

// ---------------------------------------------------------------------------
// fused per-query kernel, 4 queries per block.  Scatter goes to channel-last
// conv input x0cl[b][y][x][c=co*4+vz].
// ---------------------------------------------------------------------------
__global__ __launch_bounds__(256) void fused_query4(
    const float* __restrict__ pts_bev, const float* __restrict__ l2i,
    const float* __restrict__ qmask,
    const float* __restrict__ wT, const float* __restrict__ b_off,
    const float* __restrict__ b_sc,
    const float* __restrict__ w_agg, const float* __restrict__ b_agg,
    const int* __restrict__ vxp, const int* __restrict__ vyp, const int* __restrict__ vzp,
    const float* __restrict__ fT0, const float* __restrict__ fT1,
    const float* __restrict__ fT2, const float* __restrict__ fT3,
    float* __restrict__ xout_cl)
{
    const int bq = blockIdx.x;
    const int q0 = bq << 2;
    const int b  = q0 >> 13;
    const int t  = threadIdx.x;

    __shared__ float s_pts[4][NCIN];
    __shared__ float s_off[4][96];
    __shared__ float s_sw[4][128];
    __shared__ float s_u[4][NGP], s_v[4][NGP];
    __shared__ int   s_view[4][NGP];
    __shared__ float s_l2i[96];
    __shared__ float s_final[4][1024];
    __shared__ float s_red[4][256];
    __shared__ int   s_vx[4], s_vy[4], s_vz[4];
    __shared__ float s_qm[4];

    if (t < 4) {
        s_vx[t] = vxp[q0 + t]; s_vy[t] = vyp[q0 + t]; s_vz[t] = vzp[q0 + t];
        s_qm[t] = qmask[q0 + t];
    }
    if (t < 96) s_l2i[t] = l2i[b * 96 + t];
    __syncthreads();

    // gather BEV point features for 4 queries
    for (int i = t; i < 4 * NCIN; i += 256) {
        int qi = i >> 8, c = i & 255;
        s_pts[qi][c] = pts_bev[((size_t)(b * NCIN + c) * GYD + s_vy[qi]) * GXD + s_vx[qi]];
    }
    __syncthreads();

    // offset+scale matmuls: one output column per thread, 4 queries amortize
    // the weight stream (wT is pre-transposed: contiguous per column)
    if (t < 224) {
        const float* __restrict__ wrow = wT + t * 256;
        float bias = (t < 96) ? b_off[t] : b_sc[t - 96];
        float a0 = bias, a1 = bias, a2 = bias, a3 = bias;
        #pragma unroll 8
        for (int k = 0; k < NCIN; ++k) {
            float wk = wrow[k];
            a0 = fmaf(s_pts[0][k], wk, a0);
            a1 = fmaf(s_pts[1][k], wk, a1);
            a2 = fmaf(s_pts[2][k], wk, a2);
            a3 = fmaf(s_pts[3][k], wk, a3);
        }
        if (t < 96) {
            s_off[0][t] = a0; s_off[1][t] = a1; s_off[2][t] = a2; s_off[3][t] = a3;
        } else {
            int c2 = t - 96;
            s_sw[0][c2] = a0; s_sw[1][c2] = a1; s_sw[2][c2] = a2; s_sw[3][c2] = a3;
        }
    }
    __syncthreads();

    // softmax over L=4 + projection + first-valid-view argmax: (q, gp) per thread
    if (t < 128) {
        const int q = t >> 5, gp = t & 31;
        float a0 = s_sw[q][gp * 4 + 0], a1 = s_sw[q][gp * 4 + 1];
        float a2 = s_sw[q][gp * 4 + 2], a3 = s_sw[q][gp * 4 + 3];
        float m  = fmaxf(fmaxf(a0, a1), fmaxf(a2, a3));
        float e0 = expf(a0 - m), e1 = expf(a1 - m), e2 = expf(a2 - m), e3 = expf(a3 - m);
        float inv = 1.f / (e0 + e1 + e2 + e3);
        s_sw[q][gp * 4 + 0] = e0 * inv; s_sw[q][gp * 4 + 1] = e1 * inv;
        s_sw[q][gp * 4 + 2] = e2 * inv; s_sw[q][gp * 4 + 3] = e3 * inv;

        float cx = ((float)s_vx[q] + 0.5f) * 0.6f - 19.2f;
        float cy = ((float)s_vy[q] + 0.5f) * 0.6f - 19.2f;
        float cz = ((float)s_vz[q] + 0.5f) * 0.4f - 1.0f;
        float sx = cx + s_off[q][gp * 3 + 0] * 0.6f;
        float sy = cy + s_off[q][gp * 3 + 1] * 0.6f;
        float sz = cz + s_off[q][gp * 3 + 2] * 0.4f;

        int best = 0; float bu = 0.f, bv = 0.f; bool found = false;
        #pragma unroll
        for (int n = 0; n < NVIEW; ++n) {
            const float* M = &s_l2i[n * 16];
            float px = M[0] * sx + M[1] * sy + M[2]  * sz + M[3];
            float py = M[4] * sx + M[5] * sy + M[6]  * sz + M[7];
            float pz = M[8] * sx + M[9] * sy + M[10] * sz + M[11];
            float homo = fmaxf(pz, 1e-5f);
            float u = px / homo / 704.0f;
            float v = py / homo / 256.0f;
            bool val = (pz > 1e-5f) && (u > 0.f) && (u < 1.f) && (v > 0.f) && (v < 1.f);
            if (n == 0) { bu = u; bv = v; }
            if (val && !found) { found = true; best = n; bu = u; bv = v; }
        }
        s_view[q][gp] = best; s_u[q][gp] = bu; s_v[q][gp] = bv;
    }
    __syncthreads();

    // multi-level multi-view bilinear sampling, softmax-weighted over levels
    for (int i = t; i < 4096; i += 256) {
        const int q = i >> 10, item = i & 1023;
        const int gp = item >> 5, c = item & 31;
        const int g = gp >> 3, p = gp & 7;
        const int view = s_view[q][gp];
        const float u = s_u[q][gp], v = s_v[q][gp];
        const size_t bgv = (size_t)((b * NG + g) * NVIEW + view);
        float acc = 0.f;
        acc += s_sw[q][gp * 4 + 0] * bilin(fT0 + bgv * (32 * 88 * 32), 32, 88, u, v, c);
        acc += s_sw[q][gp * 4 + 1] * bilin(fT1 + bgv * (16 * 44 * 32), 16, 44, u, v, c);
        acc += s_sw[q][gp * 4 + 2] * bilin(fT2 + bgv * ( 8 * 22 * 32),  8, 22, u, v, c);
        acc += s_sw[q][gp * 4 + 3] * bilin(fT3 + bgv * ( 4 * 11 * 32),  4, 11, u, v, c);
        s_final[q][(p * NG + g) * NCIMG + c] = acc;
    }
    __syncthreads();

    // aggregation matmul 1024 -> 128 for 4 queries; K split across halves
    {
        const int co = t & 127, k0 = (t >> 7) * 512;
        float a0 = 0.f, a1 = 0.f, a2 = 0.f, a3 = 0.f;
        #pragma unroll 8
        for (int k = 0; k < 512; ++k) {
            float wv = w_agg[(size_t)(k0 + k) * NCOUT + co];
            a0 = fmaf(s_final[0][k0 + k], wv, a0);
            a1 = fmaf(s_final[1][k0 + k], wv, a1);
            a2 = fmaf(s_final[2][k0 + k], wv, a2);
            a3 = fmaf(s_final[3][k0 + k], wv, a3);
        }
        s_red[0][t] = a0; s_red[1][t] = a1; s_red[2][t] = a2; s_red[3][t] = a3;
    }
    __syncthreads();
    if (t < 128) {
        #pragma unroll
        for (int q = 0; q < 4; ++q) {
            float val = s_red[q][t] + s_red[q][t + 128] + b_agg[t];
            val *= s_qm[q];
            // channel-last scatter: c = co*GZ + vz
            atomicAdd(&xout_cl[((size_t)(b * 4096) + s_vy[q] * 64 + s_vx[q]) * 512
                               + t * 4 + s_vz[q]], val);
        }
    }
}

// ---------------------------------------------------------------------------
// 3x3 SAME conv + BN + ReLU via split-bf16 MFMA implicit GEMM.
// Input/output channel-last fp32 [b][y][x][C].  Block: 1 output row x 64 co,
// 4 waves (each wave: co16 x px64).  MFMA 16x16x32 bf16, 3-term hi/lo split.
// LDS: [3 rows][66 x][32 ci] hi+lo, XOR-swizzled (cb ^= (xl^(xl>>2))&3).
// ---------------------------------------------------------------------------
__global__ __launch_bounds__(256) void conv3x3_mfma(
    const float* __restrict__ xin, const u16* __restrict__ whi,
    const u16* __restrict__ wlo,
    const float* __restrict__ gam, const float* __restrict__ bet,
    float* __restrict__ yout, int CI, int CO)
{
    const int b   = blockIdx.x >> 6;
    const int y0  = blockIdx.x & 63;
    const int cob = blockIdx.y;
    const int t = threadIdx.x;
    const int w = t >> 6, l = t & 63;
    const int l15 = l & 15, kg = l >> 4;

    __shared__ __align__(16) u16 lds_hi[3 * 66 * 32];
    __shared__ __align__(16) u16 lds_lo[3 * 66 * 32];

    const int co_lane = cob * 64 + w * 16 + l15;

    f32x4 acc[4];
    #pragma unroll
    for (int m = 0; m < 4; ++m) acc[m] = (f32x4){0.f, 0.f, 0.f, 0.f};

    for (int cc = 0; cc < CI; cc += 32) {
        __syncthreads();
        // stage 3 rows x 66 x (with zero halo) x 32 ci, split into bf16 hi/lo
        for (int i = t; i < 792; i += 256) {
            const int cb = i & 3, r2 = i >> 2;
            const int xl = r2 % 66, r = r2 / 66;
            const int yi = y0 - 1 + r, xi = xl - 1;
            float v[8];
            if ((unsigned)yi < 64u && (unsigned)xi < 64u) {
                const float4* p = reinterpret_cast<const float4*>(
                    xin + ((size_t)(b * 4096 + yi * 64 + xi) * CI + cc + cb * 8));
                float4 f0 = p[0], f1 = p[1];
                v[0] = f0.x; v[1] = f0.y; v[2] = f0.z; v[3] = f0.w;
                v[4] = f1.x; v[5] = f1.y; v[6] = f1.z; v[7] = f1.w;
            } else {
                #pragma unroll
                for (int j = 0; j < 8; ++j) v[j] = 0.f;
            }
            union { u16 u[8]; uint4 q; } H, L;
            #pragma unroll
            for (int j = 0; j < 8; ++j) {
                u16 h = bf16_rne(v[j]);
                H.u[j] = h;
                L.u[j] = bf16_rne(v[j] - bf16_f(h));
            }
            const int off = (r * 66 + xl) * 32 + ((cb ^ ((xl ^ (xl >> 2)) & 3)) << 3);
            *reinterpret_cast<uint4*>(&lds_hi[off]) = H.q;
            *reinterpret_cast<uint4*>(&lds_lo[off]) = L.q;
        }
        __syncthreads();

        #pragma unroll
        for (int tap = 0; tap < 9; ++tap) {
            const int ky = tap / 3, kx = tap % 3;
            // B frag: lane (col=co_lane, k = kg*8+j) from packed [tap][co][ci]
            const size_t wo = ((size_t)tap * CO + co_lane) * CI + cc + kg * 8;
            const s16x8 Bh = *reinterpret_cast<const s16x8*>(whi + wo);
            const s16x8 Bl = *reinterpret_cast<const s16x8*>(wlo + wo);
            #pragma unroll
            for (int m = 0; m < 4; ++m) {
                // A frag: lane (row = px = m*16 + l15, k = kg*8+j)
                const int xl = m * 16 + l15 + kx;          // = x_img + 1
                const int off = (ky * 66 + xl) * 32
                              + ((kg ^ ((xl ^ (xl >> 2)) & 3)) << 3);
                const s16x8 Ah = *reinterpret_cast<const s16x8*>(&lds_hi[off]);
                const s16x8 Al = *reinterpret_cast<const s16x8*>(&lds_lo[off]);
                acc[m] = __builtin_amdgcn_mfma_f32_16x16x32_bf16(Ah, Bh, acc[m], 0, 0, 0);
                acc[m] = __builtin_amdgcn_mfma_f32_16x16x32_bf16(Ah, Bl, acc[m], 0, 0, 0);
                acc[m] = __builtin_amdgcn_mfma_f32_16x16x32_bf16(Al, Bh, acc[m], 0, 0, 0);
            }
        }
    }

    const float gsc = gam[co_lane] * 0.99999500003749978f;  // 1/sqrt(1+1e-5)
    const float bta = bet[co_lane];
    #pragma unroll
    for (int m = 0; m < 4; ++m) {
        #pragma unroll
        for (int reg = 0; reg < 4; ++reg) {
            // C/D: col = l15 (co), row = kg*4 + reg (px within 16)
            const int x = m * 16 + kg * 4 + reg;
            float val = fmaf(acc[m][reg], gsc, bta);
            yout[((size_t)(b * 4096 + y0 * 64 + x)) * CO + co_lane] = fmaxf(val, 0.f);
        }
    }
}

// channel-last [b][p][128] -> NCHW [b][128][p]
__global__ void to_nchw(const float* __restrict__ xcl, float* __restrict__ out)
{
    const int total = NB * 128 * 4096;
    for (int i = blockIdx.x * blockDim.x + threadIdx.x; i < total;
         i += gridDim.x * blockDim.x) {
        int b = i >> 19;
        int r = i & ((1 << 19) - 1);
        int co = r >> 12;
        int p = r & 4095;
        out[i] = xcl[((size_t)(b << 12) + p) * 128 + co];
    }
}

// ---------------------------------------------------------------------------
extern "C" void kernel_launch(void* const* d_in, const int* in_sizes, int n_in,
                              void* d_out, int out_size, void* d_ws, size_t ws_size,
                              hipStream_t stream)
{
    const float* feat0    = (const float*)d_in[0];
    const float* feat1    = (const float*)d_in[1];
    const float* feat2    = (const float*)d_in[2];
    const float* feat3    = (const float*)d_in[3];
    const float* pts_bev  = (const float*)d_in[4];
    const float* l2i      = (const float*)d_in[5];
    const float* qmask    = (const float*)d_in[6];
    const int*   vox_x    = (const int*)d_in[7];
    const int*   vox_y    = (const int*)d_in[8];
    const int*   vox_z    = (const int*)d_in[9];
    const float* w_off    = (const float*)d_in[10];
    const float* b_off    = (const float*)d_in[11];
    const float* w_sc     = (const float*)d_in[12];
    const float* b_sc     = (const float*)d_in[13];
    const float* w_agg    = (const float*)d_in[14];
    const float* b_agg    = (const float*)d_in[15];
    const float* conv1_w  = (const float*)d_in[16];
    const float* conv2_w  = (const float*)d_in[17];
    const float* conv3_w  = (const float*)d_in[18];
    const float* conv4_w  = (const float*)d_in[19];
    const float* bn1_g    = (const float*)d_in[20];
    const float* bn1_b    = (const float*)d_in[21];
    const float* bn2_g    = (const float*)d_in[22];
    const float* bn2_b    = (const float*)d_in[23];
    const float* bn3_g    = (const float*)d_in[24];
    const float* bn3_b    = (const float*)d_in[25];
    const float* bn4_g    = (const float*)d_in[26];
    const float* bn4_b    = (const float*)d_in[27];

    // workspace (floats), 16,287,744 fl = 65.2 MB:
    //  A [0 .. 5,744,640)           : fT0..3 (features); reused as packed conv
    //                                 weights (10,616,832 u16 = 5,308,416 fl)
    //                                 AFTER fused_query consumed the features
    //  B [5,744,640 .. 9,938,944)   : x0cl (conv1 in) -> x2cl (conv2 out)
    //  C [9,938,944 .. 12,036,096)  : x1cl (conv1 out) -> x4cl (conv4 out)
    //  D [12,036,096 .. 16,230,400) : x3cl (conv3 out)
    //  E [16,230,400 .. 16,287,744) : wT (224x256 transposed offset/scale w)
    float* ws   = (float*)d_ws;
    float* fT0  = ws;
    float* fT1  = fT0 + 4325376;
    float* fT2  = fT1 + 1081344;
    float* fT3  = fT2 + 270336;
    float* x0cl = ws + 5744640;
    float* x1cl = x0cl + 4194304;
    float* x3cl = x1cl + 2097152;
    float* wT   = x3cl + 4194304;
    float* x2cl = x0cl;
    float* x4cl = x1cl;

    u16* wpk = (u16*)ws;
    u16* wh1 = wpk;            u16* wl1 = wpk + 1179648;
    u16* wh2 = wpk + 2359296;  u16* wl2 = wpk + 3538944;
    u16* wh3 = wpk + 4718592;  u16* wl3 = wpk + 7077888;
    u16* wh4 = wpk + 9437184;  u16* wl4 = wpk + 10027008;

    pack_wT<<<224, 256, 0, stream>>>(w_off, w_sc, wT);

    transpose_feat<<<1024, 256, 0, stream>>>(feat0, fT0, 32, 88);
    transpose_feat<<< 512, 256, 0, stream>>>(feat1, fT1, 16, 44);
    transpose_feat<<< 128, 256, 0, stream>>>(feat2, fT2,  8, 22);
    transpose_feat<<<  64, 256, 0, stream>>>(feat3, fT3,  4, 11);

    hipMemsetAsync(x0cl, 0, (size_t)4194304 * sizeof(float), stream);

    fused_query4<<<NB * NQ / 4, 256, 0, stream>>>(
        pts_bev, l2i, qmask, wT, b_off, b_sc, w_agg, b_agg,
        vox_x, vox_y, vox_z, fT0, fT1, fT2, fT3, x0cl);

    // pack conv weights (features in region A are dead now)
    pack_conv_w<<<1024, 256, 0, stream>>>(conv1_w, wh1, wl1, 512, 256);
    pack_conv_w<<<1024, 256, 0, stream>>>(conv2_w, wh2, wl2, 256, 512);
    pack_conv_w<<<2048, 256, 0, stream>>>(conv3_w, wh3, wl3, 512, 512);
    pack_conv_w<<< 512, 256, 0, stream>>>(conv4_w, wh4, wl4, 512, 128);

    conv3x3_mfma<<<dim3(NB * 64, 4), 256, 0, stream>>>(
        x0cl, wh1, wl1, bn1_g, bn1_b, x1cl, 512, 256);
    conv3x3_mfma<<<dim3(NB * 64, 8), 256, 0, stream>>>(
        x1cl, wh2, wl2, bn2_g, bn2_b, x2cl, 256, 512);
    conv3x3_mfma<<<dim3(NB * 64, 8), 256, 0, stream>>>(
        x2cl, wh3, wl3, bn3_g, bn3_b, x3cl, 512, 512);
    conv3x3_mfma<<<dim3(NB * 64, 2), 256, 0, stream>>>(
        x3cl, wh4, wl4, bn4_g, bn4_b, x4cl, 512, 128);

    to_nchw<<<2048, 256, 0, stream>>>(x4cl, (float*)d_out);
}